// Round 5
// baseline (286.263 us; speedup 1.0000x reference)
//
#include <hip/hip_runtime.h>
#include <hip/hip_bf16.h>

#define HEADS  16
#define DHEAD  64
#define BATCH  4
#define SEQ    2048
#define DIM    1024
#define KVROWS 2112   // 2049 (null + SEQ) padded up to multiple of 64

typedef __hip_bfloat16 bf16;
typedef __attribute__((ext_vector_type(8))) short s8v;   // 8 x bf16 (4 VGPRs)
typedef __attribute__((ext_vector_type(4))) short s4v;   // 4 x bf16
typedef __attribute__((ext_vector_type(4))) float f4v;   // MFMA accumulator

// ---------------------------------------------------------------------------
// fp32 -> bf16 bulk convert (8 elements/thread)
// ---------------------------------------------------------------------------
__global__ void convert_kernel(const float* __restrict__ in, bf16* __restrict__ out) {
  const size_t i = ((size_t)blockIdx.x * 256 + threadIdx.x) * 8;
  const float4 a = *(const float4*)&in[i];
  const float4 b = *(const float4*)&in[i + 4];
  bf16 v[8] = {__float2bfloat16(a.x), __float2bfloat16(a.y),
               __float2bfloat16(a.z), __float2bfloat16(a.w),
               __float2bfloat16(b.x), __float2bfloat16(b.y),
               __float2bfloat16(b.z), __float2bfloat16(b.w)};
  *(s8v*)&out[i] = *(s8v*)v;
}

// ---------------------------------------------------------------------------
// Transpose+convert: fp32 [R][C] -> bf16 [C][R]; R,C multiples of 32
// ---------------------------------------------------------------------------
__global__ void transpose_kernel(const float* __restrict__ in, bf16* __restrict__ out,
                                 int R, int C) {
  __shared__ bf16 tile[32][33];
  const int c0 = blockIdx.x * 32, r0 = blockIdx.y * 32;
  const int tx = threadIdx.x, ty = threadIdx.y;
#pragma unroll
  for (int i = 0; i < 32; i += 8)
    tile[ty + i][tx] = __float2bfloat16(in[(size_t)(r0 + ty + i) * C + c0 + tx]);
  __syncthreads();
#pragma unroll
  for (int i = 0; i < 32; i += 8)
    out[(size_t)(c0 + ty + i) * R + r0 + tx] = tile[tx][ty + i];
}

// ---------------------------------------------------------------------------
// Big GEMM: C = alpha * A[M][K] @ BT[N][K]^T, 128x128 tile, BK=32, 4 waves
// (2x2), each wave a 64x64 subtile = 4x4 MFMA 16x16x32 frags. LDS rows padded
// to 36 shorts (18 dw): staging writes and frag reads both hit the 8-access
// bank floor (verified arithmetic: 18*r mod 32 spans all 16 even values).
// ---------------------------------------------------------------------------
template <typename OT>
__global__ __launch_bounds__(256) void gemm128_kernel(
    const bf16* __restrict__ A, const bf16* __restrict__ BT,
    OT* __restrict__ C, int K, int c_ld, float alpha) {
  __shared__ bf16 As[128][36];  // 9 KB
  __shared__ bf16 Bs[128][36];  // 9 KB
  const int m0 = blockIdx.x * 128, n0 = blockIdx.y * 128;
  const int t = threadIdx.x;
  const int w = t >> 6, l = t & 63, lr = l & 15, lq = l >> 4;
  const int wm = (w & 1) * 64, wn = (w >> 1) * 64;
  f4v acc[4][4] = {};
  const int srow = t >> 1, scol = (t & 1) * 16;

  for (int k0 = 0; k0 < K; k0 += 32) {
    __syncthreads();
    *(s8v*)&As[srow][scol]     = *(const s8v*)&A[(size_t)(m0 + srow) * K + k0 + scol];
    *(s8v*)&As[srow][scol + 8] = *(const s8v*)&A[(size_t)(m0 + srow) * K + k0 + scol + 8];
    *(s8v*)&Bs[srow][scol]     = *(const s8v*)&BT[(size_t)(n0 + srow) * K + k0 + scol];
    *(s8v*)&Bs[srow][scol + 8] = *(const s8v*)&BT[(size_t)(n0 + srow) * K + k0 + scol + 8];
    __syncthreads();
    s8v a[4], b[4];
#pragma unroll
    for (int mt = 0; mt < 4; mt++) a[mt] = *(const s8v*)&As[wm + mt * 16 + lr][lq * 8];
#pragma unroll
    for (int ct = 0; ct < 4; ct++) b[ct] = *(const s8v*)&Bs[wn + ct * 16 + lr][lq * 8];
#pragma unroll
    for (int mt = 0; mt < 4; mt++)
#pragma unroll
      for (int ct = 0; ct < 4; ct++)
        acc[mt][ct] = __builtin_amdgcn_mfma_f32_16x16x32_bf16(a[mt], b[ct], acc[mt][ct], 0, 0, 0);
  }
#pragma unroll
  for (int mt = 0; mt < 4; mt++)
#pragma unroll
    for (int ct = 0; ct < 4; ct++)
#pragma unroll
      for (int r = 0; r < 4; r++) {
        const int row = m0 + wm + mt * 16 + lq * 4 + r;
        const int col = n0 + wn + ct * 16 + lr;
        const float v = acc[mt][ct][r] * alpha;
        if constexpr (__is_same(OT, float)) C[(size_t)row * c_ld + col] = v;
        else                                C[(size_t)row * c_ld + col] = __float2bfloat16(v);
      }
}

// ---------------------------------------------------------------------------
// KV GEMM: kv = x @ WkvT^T (N=64), epilogue writes BOTH layouts:
//   kvbuf [b][j][d]  (row j = token+1)   and   kvbufT [b][d][j]
// Tile BM=128, BN=64, BK=32 (round-3 verified structure).
// ---------------------------------------------------------------------------
__global__ __launch_bounds__(256) void gemm_kv_kernel(
    const bf16* __restrict__ A, const bf16* __restrict__ BT,
    bf16* __restrict__ kvbuf, bf16* __restrict__ kvbufT, int K) {
  __shared__ bf16 As[128][32];
  __shared__ bf16 Bs[64][32];
  const int m0 = blockIdx.x * 128;
  const int t = threadIdx.x;
  const int w = t >> 6, l = t & 63, lr = l & 15, lq = l >> 4;
  f4v acc[2][4] = {};
  const int arow = t >> 1, acol = (t & 1) * 16;
  const int brow = t >> 2, bcol = (t & 3) * 8;

  for (int k0 = 0; k0 < K; k0 += 32) {
    __syncthreads();
    *(s8v*)&As[arow][acol]     = *(const s8v*)&A[(size_t)(m0 + arow) * K + k0 + acol];
    *(s8v*)&As[arow][acol + 8] = *(const s8v*)&A[(size_t)(m0 + arow) * K + k0 + acol + 8];
    *(s8v*)&Bs[brow][bcol]     = *(const s8v*)&BT[(size_t)brow * K + k0 + bcol];
    __syncthreads();
    s8v a0 = *(const s8v*)&As[w * 32 + lr][lq * 8];
    s8v a1 = *(const s8v*)&As[w * 32 + 16 + lr][lq * 8];
#pragma unroll
    for (int ct = 0; ct < 4; ct++) {
      s8v bf = *(const s8v*)&Bs[ct * 16 + lr][lq * 8];
      acc[0][ct] = __builtin_amdgcn_mfma_f32_16x16x32_bf16(a0, bf, acc[0][ct], 0, 0, 0);
      acc[1][ct] = __builtin_amdgcn_mfma_f32_16x16x32_bf16(a1, bf, acc[1][ct], 0, 0, 0);
    }
  }
#pragma unroll
  for (int mt = 0; mt < 2; mt++)
#pragma unroll
    for (int ct = 0; ct < 4; ct++)
#pragma unroll
      for (int r = 0; r < 4; r++) {
        const int m = m0 + w * 32 + mt * 16 + lq * 4 + r;   // 0..8191
        const int col = ct * 16 + lr;                        // d
        const int bb = m >> 11, jj = (m & 2047) + 1;
        const bf16 v = __float2bfloat16(acc[mt][ct][r]);
        kvbuf [(size_t)(bb * KVROWS + jj) * DHEAD + col] = v;
        kvbufT[(size_t)(bb * DHEAD + col) * KVROWS + jj] = v;
      }
}

// ---------------------------------------------------------------------------
// Fill row 0 (null_kv) and tail rows 2049..2111 (zeros) in BOTH kv layouts.
// ---------------------------------------------------------------------------
__global__ void fill_null_tail_kernel(const float* __restrict__ null_kv,
                                      bf16* __restrict__ kvbuf,
                                      bf16* __restrict__ kvbufT) {
  const int idx = blockIdx.x * 256 + threadIdx.x;  // [0, 4*64*64)
  const int d = idx & 63;
  const int s = (idx >> 6) & 63;
  const int b = idx >> 12;
  const int row = (s == 0) ? 0 : 2048 + s;
  const bf16 v = (s == 0) ? __float2bfloat16(null_kv[d]) : __float2bfloat16(0.f);
  kvbuf [(size_t)(b * KVROWS + row) * DHEAD + d] = v;
  kvbufT[(size_t)(b * DHEAD + d) * KVROWS + row] = v;
}

// ---------------------------------------------------------------------------
// Transposed flash attention, BM=128 q-rows/block (2 i-groups per lane).
// S^T = KV.Q^T; O^T = KV^T.P^T. KV^T comes pre-transposed from global
// (kvbufT) -> all LDS loop traffic is b128/b64 at the bank floor, no scalar
// gathers, no in-kernel transpose. q pre-scaled by 0.125*log2e; exp2 softmax.
// ---------------------------------------------------------------------------
__global__ __launch_bounds__(256) void attn_kernel(
    const bf16* __restrict__ q,    // [B*SEQ][DIM] (pre-scaled)
    const bf16* __restrict__ kv,   // [B][KVROWS][64]
    const bf16* __restrict__ kvT,  // [B][64][KVROWS]
    bf16* __restrict__ o) {        // [B*SEQ][DIM]
  __shared__ bf16 kvs [64][72];    // kv[j][d]   9 KB
  __shared__ bf16 kvsT[64][72];    // kv^T[d][j] 9 KB
  __shared__ bf16 Ps[4][32][72];   // per-wave P^T as [i-local][j] 18 KB
  const int t = threadIdx.x, w = t >> 6, l = t & 63, lr = l & 15, lq = l >> 4;
  const int blk = blockIdx.x;
  const int qt = 15 - (blk >> 6);          // longest q-tiles first
  const int hb = blk & 63, h = hb >> 2, b = hb & 3;
  const int q0 = qt * 128;

  // Q B-fragments for both i-groups, direct from global
  s8v qb[2][2];
#pragma unroll
  for (int g = 0; g < 2; g++) {
    const bf16* qrow = q + ((size_t)(b * SEQ) + q0 + w * 32 + g * 16 + lr) * DIM + h * DHEAD;
    qb[g][0] = *(const s8v*)&qrow[lq * 8];
    qb[g][1] = *(const s8v*)&qrow[32 + lq * 8];
  }

  f4v oaccT[2][4] = {};
  float m_i[2] = {-1e30f, -1e30f}, l_i[2] = {0.f, 0.f};

  const bf16* kvb  = kv  + (size_t)b * KVROWS * DHEAD;
  const bf16* kvTb = kvT + (size_t)b * DHEAD * KVROWS;
  const int jend = q0 + 129;
  const int srow = t >> 2, scol = (t & 3) * 16;

  for (int j0 = 0; j0 < jend; j0 += 64) {
    __syncthreads();  // prior iteration's kvs/kvsT readers done
    *(s8v*)&kvs[srow][scol]      = *(const s8v*)&kvb[(size_t)(j0 + srow) * DHEAD + scol];
    *(s8v*)&kvs[srow][scol + 8]  = *(const s8v*)&kvb[(size_t)(j0 + srow) * DHEAD + scol + 8];
    *(s8v*)&kvsT[srow][scol]     = *(const s8v*)&kvTb[(size_t)srow * KVROWS + j0 + scol];
    *(s8v*)&kvsT[srow][scol + 8] = *(const s8v*)&kvTb[(size_t)srow * KVROWS + j0 + scol + 8];
    __syncthreads();

    // S^T[j][i] per i-group
    f4v st[2][4];
#pragma unroll
    for (int jt = 0; jt < 4; jt++) {
      s8v a0 = *(const s8v*)&kvs[jt * 16 + lr][lq * 8];
      s8v a1 = *(const s8v*)&kvs[jt * 16 + lr][32 + lq * 8];
#pragma unroll
      for (int g = 0; g < 2; g++) {
        f4v z = {0.f, 0.f, 0.f, 0.f};
        z = __builtin_amdgcn_mfma_f32_16x16x32_bf16(a0, qb[g][0], z, 0, 0, 0);
        z = __builtin_amdgcn_mfma_f32_16x16x32_bf16(a1, qb[g][1], z, 0, 0, 0);
        st[g][jt] = z;
      }
    }

    // mask + online softmax (log2 domain), per i-group
#pragma unroll
    for (int g = 0; g < 2; g++) {
      const int ig = q0 + w * 32 + g * 16 + lr;
      float mx = -1e30f;
#pragma unroll
      for (int jt = 0; jt < 4; jt++)
#pragma unroll
        for (int r = 0; r < 4; r++) {
          const int jg = j0 + jt * 16 + lq * 4 + r;
          float v = (jg > ig + 1) ? -1e30f : st[g][jt][r];
          st[g][jt][r] = v;
          mx = fmaxf(mx, v);
        }
      mx = fmaxf(mx, __shfl_xor(mx, 16));
      mx = fmaxf(mx, __shfl_xor(mx, 32));
      const float mnew = fmaxf(m_i[g], mx);
      const float alpha = exp2f(m_i[g] - mnew);
      m_i[g] = mnew;
      float rs = 0.f;
#pragma unroll
      for (int jt = 0; jt < 4; jt++)
#pragma unroll
        for (int r = 0; r < 4; r++) {
          const float pv = exp2f(st[g][jt][r] - mnew);
          st[g][jt][r] = pv;
          rs += pv;
        }
      rs += __shfl_xor(rs, 16);
      rs += __shfl_xor(rs, 32);
      l_i[g] = l_i[g] * alpha + rs;
#pragma unroll
      for (int dt = 0; dt < 4; dt++)
#pragma unroll
        for (int r = 0; r < 4; r++) oaccT[g][dt][r] *= alpha;

      // P^T -> Ps[w] rows g*16+lr (wave-local), b64 writes
#pragma unroll
      for (int jt = 0; jt < 4; jt++) {
        s4v pk;
#pragma unroll
        for (int r = 0; r < 4; r++) {
          bf16 h16 = __float2bfloat16(st[g][jt][r]);
          pk[r] = *(short*)&h16;
        }
        *(s4v*)&Ps[w][g * 16 + lr][jt * 16 + lq * 4] = pk;
      }
    }

    // O^T[d][i] += sum_j kv^T[d][j] * P^T[j][i]
    s8v pb[2][2];
#pragma unroll
    for (int g = 0; g < 2; g++) {
      pb[g][0] = *(const s8v*)&Ps[w][g * 16 + lr][lq * 8];
      pb[g][1] = *(const s8v*)&Ps[w][g * 16 + lr][32 + lq * 8];
    }
#pragma unroll
    for (int dt = 0; dt < 4; dt++) {
      s8v a0 = *(const s8v*)&kvsT[dt * 16 + lr][lq * 8];
      s8v a1 = *(const s8v*)&kvsT[dt * 16 + lr][32 + lq * 8];
#pragma unroll
      for (int g = 0; g < 2; g++) {
        oaccT[g][dt] = __builtin_amdgcn_mfma_f32_16x16x32_bf16(a0, pb[g][0], oaccT[g][dt], 0, 0, 0);
        oaccT[g][dt] = __builtin_amdgcn_mfma_f32_16x16x32_bf16(a1, pb[g][1], oaccT[g][dt], 0, 0, 0);
      }
    }
  }

  // epilogue: O^T -> wave-local LDS transpose -> coalesced 32B stores
#pragma unroll
  for (int g = 0; g < 2; g++) {
    const float inv = 1.0f / l_i[g];
#pragma unroll
    for (int dt = 0; dt < 4; dt++) {
      s4v pk;
#pragma unroll
      for (int r = 0; r < 4; r++) {
        bf16 h16 = __float2bfloat16(oaccT[g][dt][r] * inv);
        pk[r] = *(short*)&h16;
      }
      *(s4v*)&Ps[w][g * 16 + lr][dt * 16 + lq * 4] = pk;  // Ps[w][i][d] = O
    }
  }
#pragma unroll
  for (int g = 0; g < 2; g++) {
    const int orow = l >> 2, od = (l & 3) * 16;
    s8v o0 = *(const s8v*)&Ps[w][g * 16 + orow][od];
    s8v o1 = *(const s8v*)&Ps[w][g * 16 + orow][od + 8];
    bf16* op = o + ((size_t)(b * SEQ) + q0 + w * 32 + g * 16 + orow) * DIM + h * DHEAD + od;
    *(s8v*)&op[0] = o0;
    *(s8v*)&op[8] = o1;
  }
}

// ---------------------------------------------------------------------------
// Inputs fp32, output fp32 (32 MB d_out). d_out doubles as staging:
//   q (bf16, 16 MB) @ d_out+0, kvbufT (1.06 MB) @ d_out+16MB — both dead
//   before the final fp32 GEMM overwrites d_out.
// Workspace 35.1 MB (proven): att@0 16MB (WqT@0, WkvT@+2MB alias, dead
// pre-attn) | xb@16MB | WoutT@32MB | kvbuf@34MB.
// ---------------------------------------------------------------------------
extern "C" void kernel_launch(void* const* d_in, const int* in_sizes, int n_in,
                              void* d_out, int out_size, void* d_ws, size_t ws_size,
                              hipStream_t stream) {
  const float* x       = (const float*)d_in[0];
  const float* Wq      = (const float*)d_in[1];
  const float* Wkv     = (const float*)d_in[2];
  const float* null_kv = (const float*)d_in[3];
  const float* Wout    = (const float*)d_in[4];
  float* out = (float*)d_out;

  bf16* q      = (bf16*)d_out;                                   // 16 MB
  bf16* kvbufT = (bf16*)((char*)d_out + (size_t)16 * 1024 * 1024);  // 1.06 MB
  char* p = (char*)d_ws;
  bf16* att   = (bf16*)p;
  bf16* xb    = (bf16*)(p + (size_t)16 * 1024 * 1024);
  bf16* WoutT = (bf16*)(p + (size_t)32 * 1024 * 1024);
  bf16* kvbuf = (bf16*)(p + (size_t)34 * 1024 * 1024);
  bf16* WqT   = att;
  bf16* WkvT  = att + (size_t)DIM * DIM;

  convert_kernel<<<(BATCH * SEQ * DIM) / (256 * 8), 256, 0, stream>>>(x, xb);

  const dim3 tb(32, 8);
  transpose_kernel<<<dim3(32, 32), tb, 0, stream>>>(Wq,   WqT,   DIM, DIM);
  transpose_kernel<<<dim3(2, 32),  tb, 0, stream>>>(Wkv,  WkvT,  DIM, DHEAD);
  transpose_kernel<<<dim3(32, 32), tb, 0, stream>>>(Wout, WoutT, DIM, DIM);

  // q = x @ Wq * (DHEAD^-0.5 * log2e) -> bf16 in d_out
  gemm128_kernel<bf16><<<dim3(64, 8), 256, 0, stream>>>(xb, WqT, q, DIM, DIM,
                                                        0.125f * 1.44269504089f);
  // kv = x @ Wkv -> kvbuf + kvbufT (dual-layout epilogue)
  gemm_kv_kernel<<<64, 256, 0, stream>>>(xb, WkvT, kvbuf, kvbufT, DIM);
  fill_null_tail_kernel<<<(BATCH * 64 * 64) / 256, 256, 0, stream>>>(null_kv, kvbuf, kvbufT);
  // attention: grid = 16 q-tiles x (h,b)
  attn_kernel<<<BATCH * HEADS * (SEQ / 128), 256, 0, stream>>>(q, kvbuf, kvbufT, att);
  // out = att @ Wout -> d_out fp32 (q, kvbufT dead)
  gemm128_kernel<float><<<dim3(64, 8), 256, 0, stream>>>(att, WoutT, out, DIM, DIM, 1.0f);
}